// Round 1
// 949.959 us; speedup vs baseline: 1.2211x; 1.2211x over previous
//
#include <hip/hip_runtime.h>
#include <hip/hip_bf16.h>

typedef unsigned short u16;
typedef __attribute__((ext_vector_type(8))) short bf16x8;   // 8 bf16 = 4 VGPRs
typedef __attribute__((ext_vector_type(8))) unsigned short u16x8;
typedef __attribute__((ext_vector_type(4))) float f32x4;

#define NHh 12
#define KDd 64
#define Bb 64
#define Nn 1024
#define Cc 768
#define Oo 1548          // (1+2*64)*12
#define Mm 65536         // B*N

__device__ __forceinline__ float bf2f(u16 u) {
    union { unsigned int i; float f; } x; x.i = ((unsigned int)u) << 16; return x.f;
}
__device__ __forceinline__ u16 f2bf(float f) {
    union { float f; unsigned int i; } x; x.f = f;
    unsigned int r = x.i + 0x7fffu + ((x.i >> 16) & 1u);  // RNE
    return (u16)(r >> 16);
}
// packed f32x2 -> bf16x2 (RNE), src0 in low half
__device__ __forceinline__ unsigned int cvtpk(float a, float b) {
    unsigned int r;
    asm("v_cvt_pk_bf16_f32 %0, %1, %2" : "=v"(r) : "v"(a), "v"(b));
    return r;
}

__device__ __forceinline__ void async16(const u16* g, u16* l) {
    __builtin_amdgcn_global_load_lds(
        (const __attribute__((address_space(1))) void*)g,
        (__attribute__((address_space(3))) void*)l, 16, 0, 0);
}

// ---- dtype detect: even-index u16s of a bf16 buffer are bf16 values (narrow
// exponent band); of an fp32 buffer they are uniform mantissa bits (~25% band hit).
__global__ void detect_kernel(const u16* __restrict__ w, int* __restrict__ flag)
{
    __shared__ int cnt;
    if (threadIdx.x == 0) cnt = 0;
    __syncthreads();
    int c = 0;
#pragma unroll
    for (int i = 0; i < 4; ++i) {
        const u16 u = w[(threadIdx.x * 4 + i) * 2];
        const int e = (u >> 7) & 0xFF;
        c += ((e >= 0x60 && e <= 0x9F) || u == 0) ? 1 : 0;
    }
    atomicAdd(&cnt, c);
    __syncthreads();
    if (threadIdx.x == 0) flag[0] = (cnt >= 160) ? 1 : 0;   // 1 => bf16 buffers
}

// C[m,o] = sum_k A[m,k]*B[o,k] (+ bias[o]); row-major, contract last dims.
// ADUAL=1: A may be bf16 or fp32 per flag. ADUAL=0: A is always internal bf16.
// EPI=1: scatter into Qf (fp32), Kb (bf16), Vb (bf16, packed m x 768)
// EPI=2: store bf16 to Cout16 or fp32 to Cout32 per flag.
// LDS layout is XOR-swizzled: lds[r][slot s] holds A[r][chunk s^(r&7)]
// (chunk = 8 elems = 16 B). Reg-staged path writes swizzled slots directly;
// global_load_lds path pre-swizzles the GLOBAL source column (rule #21).
template <int EPI, int ADUAL>
__global__ __launch_bounds__(256, 4) void gemm_bt(
    const void* __restrict__ Av, const void* __restrict__ Bv,
    const void* __restrict__ biasv, const int* __restrict__ flagp,
    int Nout, int K, int lda, int ldb, int ntn,
    float* __restrict__ Qf, u16* __restrict__ Kb, u16* __restrict__ Vb,
    u16* __restrict__ Cout16, float* __restrict__ Cout32, int ldc)
{
    __shared__ __align__(16) u16 lA[128 * 64];
    __shared__ __align__(16) u16 lB[128 * 64];

    const int isbf = flagp[0];

    const u16*   A16 = (const u16*)Av;
    const float* A32 = (const float*)Av;
    const u16*   B16 = (const u16*)Bv;
    const float* B32 = (const float*)Bv;

    const int t = threadIdx.x;
    const int lane = t & 63, wave = t >> 6;

    // XCD-chunked bijective swizzle (grid is a multiple of 8): blocks sharing
    // an A-tile (same tm) become consecutive on ONE XCD -> A-tile L2-resident.
    int bid = blockIdx.x;
    {
        const int nwg = (int)gridDim.x;   // multiple of 8
        const int cpx = nwg >> 3;
        bid = (bid & 7) * cpx + (bid >> 3);
    }
    const int tm = bid / ntn, tn = bid % ntn;
    const int m0 = tm * 128, o0 = tn * 128;

    const int srow = t >> 3;        // 0..31  (staging row within 32-row chunk)
    const int scol = (t & 7) * 8;   // staging col (elements), linear slot = t&7
    const int ssw  = (((t & 7) ^ (srow & 7)) * 8); // swizzled slot (elements)

    const int R0 = (wave >> 1) * 64, C0 = (wave & 1) * 64;
    const int lr = lane & 15, lq = lane >> 4;
    const int sw8 = lr & 7;         // row&7 for all fragment rows this lane reads

    f32x4 acc[4][4];
    const f32x4 zero = {0.f, 0.f, 0.f, 0.f};
#pragma unroll
    for (int i = 0; i < 4; ++i)
#pragma unroll
        for (int j = 0; j < 4; ++j) acc[i][j] = zero;

    for (int k0 = 0; k0 < K; k0 += 64) {
        // ---- stage A tile (128x64)
        if (ADUAL == 0 || isbf) {
            // linear LDS dest (lane*16), source column pre-swizzled
#pragma unroll
            for (int i = 0; i < 4; ++i)
                async16(A16 + (size_t)(m0 + i * 32 + srow) * lda + k0 + ssw,
                        &lA[(i * 32 + srow) * 64 + scol]);
        } else {
#pragma unroll
            for (int i = 0; i < 4; ++i) {
                const float* p = A32 + (size_t)(m0 + i * 32 + srow) * lda + k0 + scol;
                const f32x4 a0 = *(const f32x4*)p;
                const f32x4 a1 = *(const f32x4*)(p + 4);
                union { unsigned int u[4]; u16x8 v; } pk;
                pk.u[0] = cvtpk(a0[0], a0[1]);
                pk.u[1] = cvtpk(a0[2], a0[3]);
                pk.u[2] = cvtpk(a1[0], a1[1]);
                pk.u[3] = cvtpk(a1[2], a1[3]);
                *(u16x8*)&lA[(i * 32 + srow) * 64 + ssw] = pk.v;
            }
        }
        // ---- stage B tile (128x64), clamp out-of-range rows (stores masked later)
        if (isbf) {
#pragma unroll
            for (int i = 0; i < 4; ++i) {
                int o = o0 + i * 32 + srow;
                if (o > Nout - 1) o = Nout - 1;
                async16(B16 + (size_t)o * ldb + k0 + ssw, &lB[(i * 32 + srow) * 64 + scol]);
            }
        } else {
#pragma unroll
            for (int i = 0; i < 4; ++i) {
                int o = o0 + i * 32 + srow;
                if (o > Nout - 1) o = Nout - 1;
                const float* p = B32 + (size_t)o * ldb + k0 + scol;
                const f32x4 b0 = *(const f32x4*)p;
                const f32x4 b1 = *(const f32x4*)(p + 4);
                union { unsigned int u[4]; u16x8 v; } pk;
                pk.u[0] = cvtpk(b0[0], b0[1]);
                pk.u[1] = cvtpk(b0[2], b0[3]);
                pk.u[2] = cvtpk(b1[0], b1[1]);
                pk.u[3] = cvtpk(b1[2], b1[3]);
                *(u16x8*)&lB[(i * 32 + srow) * 64 + ssw] = pk.v;
            }
        }
        asm volatile("s_waitcnt vmcnt(0)" ::: "memory");
        __syncthreads();

#pragma unroll
        for (int kk = 0; kk < 2; ++kk) {
            bf16x8 af[4], bfr[4];
#pragma unroll
            for (int i = 0; i < 4; ++i) {
                const int sl = (((kk * 4 + lq) ^ sw8) * 8);
                af[i] = *(const bf16x8*)&lA[(R0 + i * 16 + lr) * 64 + sl];
            }
#pragma unroll
            for (int j = 0; j < 4; ++j) {
                const int sl = (((kk * 4 + lq) ^ sw8) * 8);
                bfr[j] = *(const bf16x8*)&lB[(C0 + j * 16 + lr) * 64 + sl];
            }
#pragma unroll
            for (int i = 0; i < 4; ++i)
#pragma unroll
                for (int j = 0; j < 4; ++j)
                    acc[i][j] = __builtin_amdgcn_mfma_f32_16x16x32_bf16(af[i], bfr[j], acc[i][j], 0, 0, 0);
        }
        __syncthreads();
    }

    // epilogue: C/D layout col=lane&15, row=(lane>>4)*4+reg
#pragma unroll
    for (int i = 0; i < 4; ++i) {
#pragma unroll
        for (int j = 0; j < 4; ++j) {
            const int ob = o0 + C0 + j * 16 + lr;
            float bv = 0.f;
            if (ob < Nout)
                bv = isbf ? bf2f(((const u16*)biasv)[ob]) : ((const float*)biasv)[ob];
#pragma unroll
            for (int r = 0; r < 4; ++r) {
                const int row = m0 + R0 + i * 16 + lq * 4 + r;
                const float val = acc[i][j][r] + bv;
                if (EPI == 1) {
                    if (ob < Nout) {
                        const int h = ob / 129;
                        const int rr = ob - h * 129;
                        const size_t mh = (size_t)row * 12 + h;
                        if (rr == 0)       Qf[mh] = val;
                        else if (rr <= 64) Kb[mh * 64 + (rr - 1)]  = f2bf(val);
                        else               Vb[mh * 64 + (rr - 65)] = f2bf(val);
                    }
                } else {
                    if (isbf) Cout16[(size_t)row * ldc + ob] = f2bf(val);
                    else      Cout32[(size_t)row * ldc + ob] = val;
                }
            }
        }
    }
}

// one block per (b,h): softmax over n of q, then cv[d] = sum_n p_n * wcv_n * K[b,n,h,d] / sum
__global__ __launch_bounds__(256) void softmax_cv_kernel(
    const float* __restrict__ Qf, const u16* __restrict__ Kb,
    const void* __restrict__ wcvv, const int* __restrict__ flagp,
    float* __restrict__ cv)
{
    const int isbf = flagp[0];
    const int bh = blockIdx.x;            // 0..767
    const int b = bh / NHh, h = bh - (bh / NHh) * NHh;
    const int t = threadIdx.x;

    __shared__ float sp[1024];
    __shared__ float red[256];

    float q[4];
#pragma unroll
    for (int i = 0; i < 4; ++i) {
        const int n = t + i * 256;
        q[i] = Qf[(size_t)(b * Nn + n) * NHh + h];
    }
    float mx = fmaxf(fmaxf(q[0], q[1]), fmaxf(q[2], q[3]));
    red[t] = mx; __syncthreads();
    for (int off = 128; off; off >>= 1) {
        if (t < off) red[t] = fmaxf(red[t], red[t + off]);
        __syncthreads();
    }
    mx = red[0];
    __syncthreads();

    float sloc = 0.f;
#pragma unroll
    for (int i = 0; i < 4; ++i) {
        const int n = t + i * 256;
        const float e = __expf(q[i] - mx);
        sloc += e;
        const float wv = isbf ? bf2f(((const u16*)wcvv)[n]) : ((const float*)wcvv)[n];
        sp[n] = e * wv;
    }
    red[t] = sloc; __syncthreads();
    for (int off = 128; off; off >>= 1) {
        if (t < off) red[t] += red[t + off];
        __syncthreads();
    }
    const float s = red[0];
    __syncthreads();

    const int d = t & 63, g = t >> 6;     // 4 n-groups of 256
    const u16* Kp = Kb + ((size_t)(b * Nn + g * 256) * NHh + h) * 64 + d;
    const float* pp = sp + g * 256;
    float acc = 0.f;
#pragma unroll 8
    for (int n = 0; n < 256; ++n)
        acc = fmaf(bf2f(Kp[(size_t)n * 768]), pp[n], acc);

    red[t] = acc; __syncthreads();
    if (t < 64) {
        const float tot = red[t] + red[t + 64] + red[t + 128] + red[t + 192];
        cv[(size_t)bh * 64 + t] = tot / s;
    }
}

// in-place V[m, c] = relu(V[m,c]) * cv[(b*12+h)*64+d],  c = h*64+d, b = m>>10
__global__ __launch_bounds__(256) void relu_cv_kernel(
    u16* __restrict__ Vb, const float* __restrict__ cv)
{
    const size_t idx = ((size_t)blockIdx.x * 256 + threadIdx.x) * 8;
    const int c = (int)(idx % 768);
    const size_t m = idx / 768;
    const int b = (int)(m >> 10);
    const int h = c >> 6, d0 = c & 63;
    const float* cvp = cv + ((size_t)b * NHh + h) * 64 + d0;

    u16x8 r = *(const u16x8*)(Vb + idx);
#pragma unroll
    for (int i = 0; i < 8; ++i) {
        const float f = fmaxf(bf2f(r[i]), 0.f) * cvp[i];
        r[i] = f2bf(f);
    }
    *(u16x8*)(Vb + idx) = r;
}

extern "C" void kernel_launch(void* const* d_in, const int* in_sizes, int n_in,
                              void* d_out, int out_size, void* d_ws, size_t ws_size,
                              hipStream_t stream)
{
    const void* x     = d_in[0];
    const void* w_qkv = d_in[1];
    const void* b_qkv = d_in[2];
    const void* w_cv  = d_in[3];
    const void* w_out = d_in[4];
    const void* b_out = d_in[5];

    char* w = (char*)d_ws;
    float* Qf = (float*)w;                                   // 65536*12*4   = 3,145,728 B
    u16*   Kb = (u16*)(w + 3145728);                          // 65536*768*2  = 100,663,296 B
    u16*   Vb = (u16*)(w + 3145728 + 100663296);              // 100,663,296 B
    float* cv = (float*)(w + 3145728 + 2ll * 100663296);      // 768*64*4     = 196,608 B
    int* flag = (int*)(w + 3145728 + 2ll * 100663296 + 196608);

    // dtype detect (bf16 vs fp32 buffers)
    detect_kernel<<<1, 64, 0, stream>>>((const u16*)w_qkv, flag);

    // GEMM1: qkv = x @ w_qkv^T + b_qkv, scattered into Qf/Kb/Vb
    gemm_bt<1, 1><<<512 * 13, 256, 0, stream>>>(x, w_qkv, b_qkv, flag,
        Oo, Cc, Cc, Cc, 13, Qf, Kb, Vb, nullptr, nullptr, 0);

    // softmax over n + cv reduction
    softmax_cv_kernel<<<Bb * NHh, 256, 0, stream>>>(Qf, Kb, w_cv, flag, cv);

    // t = relu(v) * cv, in place on Vb
    relu_cv_kernel<<<(Mm * 768) / (256 * 8), 256, 0, stream>>>(Vb, cv);

    // GEMM2: out = t @ w_out^T + b_out
    gemm_bt<2, 0><<<512 * 6, 256, 0, stream>>>(Vb, w_out, b_out, flag,
        Cc, Cc, Cc, Cc, 6, nullptr, nullptr, nullptr, (u16*)d_out, (float*)d_out, Cc);
}

// Round 2
// 751.073 us; speedup vs baseline: 1.5445x; 1.2648x over previous
//
#include <hip/hip_runtime.h>
#include <hip/hip_bf16.h>

typedef unsigned short u16;
typedef __attribute__((ext_vector_type(8))) short bf16x8;   // 8 bf16 = 4 VGPRs
typedef __attribute__((ext_vector_type(8))) unsigned short u16x8;
typedef __attribute__((ext_vector_type(4))) float f32x4;

#define NHh 12
#define KDd 64
#define Bb 64
#define Nn 1024
#define Cc 768
#define Oo 1548          // (1+2*64)*12
#define Mm 65536         // B*N

__device__ __forceinline__ float bf2f(u16 u) {
    union { unsigned int i; float f; } x; x.i = ((unsigned int)u) << 16; return x.f;
}
__device__ __forceinline__ u16 f2bf(float f) {
    union { float f; unsigned int i; } x; x.f = f;
    unsigned int r = x.i + 0x7fffu + ((x.i >> 16) & 1u);  // RNE
    return (u16)(r >> 16);
}
// packed f32x2 -> bf16x2 (RNE), src0 in low half
__device__ __forceinline__ unsigned int cvtpk(float a, float b) {
    unsigned int r;
    asm("v_cvt_pk_bf16_f32 %0, %1, %2" : "=v"(r) : "v"(a), "v"(b));
    return r;
}

__device__ __forceinline__ void async16(const u16* g, u16* l) {
    __builtin_amdgcn_global_load_lds(
        (const __attribute__((address_space(1))) void*)g,
        (__attribute__((address_space(3))) void*)l, 16, 0, 0);
}

// ---- dtype detect: even-index u16s of a bf16 buffer are bf16 values (narrow
// exponent band); of an fp32 buffer they are uniform mantissa bits (~25% band hit).
__global__ void detect_kernel(const u16* __restrict__ w, int* __restrict__ flag)
{
    __shared__ int cnt;
    if (threadIdx.x == 0) cnt = 0;
    __syncthreads();
    int c = 0;
#pragma unroll
    for (int i = 0; i < 4; ++i) {
        const u16 u = w[(threadIdx.x * 4 + i) * 2];
        const int e = (u >> 7) & 0xFF;
        c += ((e >= 0x60 && e <= 0x9F) || u == 0) ? 1 : 0;
    }
    atomicAdd(&cnt, c);
    __syncthreads();
    if (threadIdx.x == 0) flag[0] = (cnt >= 160) ? 1 : 0;   // 1 => bf16 buffers
}

// fp32 -> bf16 streaming convert, 16 elems/thread. Early-out if inputs are bf16.
__global__ __launch_bounds__(256) void cvt_kernel(
    const float* __restrict__ src, u16* __restrict__ dst, int n16,
    const int* __restrict__ flagp)
{
    if (flagp[0]) return;
    const int i = blockIdx.x * 256 + threadIdx.x;
    if (i >= n16) return;
    const float* p = src + (size_t)i * 16;
    const f32x4 a0 = *(const f32x4*)p;
    const f32x4 a1 = *(const f32x4*)(p + 4);
    const f32x4 a2 = *(const f32x4*)(p + 8);
    const f32x4 a3 = *(const f32x4*)(p + 12);
    union { unsigned int u[8]; u16x8 v[2]; } pk;
    pk.u[0] = cvtpk(a0[0], a0[1]); pk.u[1] = cvtpk(a0[2], a0[3]);
    pk.u[2] = cvtpk(a1[0], a1[1]); pk.u[3] = cvtpk(a1[2], a1[3]);
    pk.u[4] = cvtpk(a2[0], a2[1]); pk.u[5] = cvtpk(a2[2], a2[3]);
    pk.u[6] = cvtpk(a3[0], a3[1]); pk.u[7] = cvtpk(a3[2], a3[3]);
    *(u16x8*)(dst + (size_t)i * 16)     = pk.v[0];
    *(u16x8*)(dst + (size_t)i * 16 + 8) = pk.v[1];
}

// C[m,o] = sum_k A[m,k]*B[o,k] (+ bias[o]); row-major, contract last dims.
// A/B are bf16: either the original input (isbf) or the pre-converted buffer.
// Staging is pure global_load_lds width-16: linear LDS dest (lane*16), source
// column pre-swizzled; ds_read applies the matching XOR (rule #21, verified r1:
// SQ_LDS_BANK_CONFLICT == 0).
// EPI=1: scatter into Qf (fp32), Kb (bf16), Vb (bf16, packed m x 768)
// EPI=2: store bf16 to Cout16 or fp32 to Cout32 per flag.
template <int EPI>
__global__ __launch_bounds__(256, 4) void gemm_bt(
    const void* __restrict__ Aorig, const u16* __restrict__ Acvt,
    const void* __restrict__ Borig, const u16* __restrict__ Bcvt,
    const void* __restrict__ biasv, const int* __restrict__ flagp,
    int Nout, int K, int lda, int ldb, int ntn,
    float* __restrict__ Qf, u16* __restrict__ Kb, u16* __restrict__ Vb,
    u16* __restrict__ Cout16, float* __restrict__ Cout32, int ldc)
{
    __shared__ __align__(16) u16 lA[128 * 64];
    __shared__ __align__(16) u16 lB[128 * 64];

    const int isbf = flagp[0];
    const u16* A  = isbf ? (const u16*)Aorig : Acvt;
    const u16* Bp = isbf ? (const u16*)Borig : Bcvt;

    const int t = threadIdx.x;
    const int lane = t & 63, wave = t >> 6;

    // XCD-chunked bijective swizzle (grid is a multiple of 8): blocks sharing
    // an A-tile (same tm) become consecutive on ONE XCD -> A-tile L2-resident.
    int bid = blockIdx.x;
    {
        const int nwg = (int)gridDim.x;   // multiple of 8
        const int cpx = nwg >> 3;
        bid = (bid & 7) * cpx + (bid >> 3);
    }
    const int tm = bid / ntn, tn = bid % ntn;
    const int m0 = tm * 128, o0 = tn * 128;

    const int srow = t >> 3;        // 0..31  (staging row within 32-row chunk)
    const int scol = (t & 7) * 8;   // staging col (elements), linear slot = t&7
    const int ssw  = (((t & 7) ^ (srow & 7)) * 8); // swizzled source col (elements)

    const int R0 = (wave >> 1) * 64, C0 = (wave & 1) * 64;
    const int lr = lane & 15, lq = lane >> 4;
    const int sw8 = lr & 7;         // row&7 for all fragment rows this lane reads

    // hoisted staging addresses
    const u16* aSrc[4];
    const u16* bSrc[4];
#pragma unroll
    for (int i = 0; i < 4; ++i) {
        aSrc[i] = A + (size_t)(m0 + i * 32 + srow) * lda + ssw;
        int o = o0 + i * 32 + srow;
        if (o > Nout - 1) o = Nout - 1;
        bSrc[i] = Bp + (size_t)o * ldb + ssw;
    }

    f32x4 acc[4][4];
    const f32x4 zero = {0.f, 0.f, 0.f, 0.f};
#pragma unroll
    for (int i = 0; i < 4; ++i)
#pragma unroll
        for (int j = 0; j < 4; ++j) acc[i][j] = zero;

    for (int k0 = 0; k0 < K; k0 += 64) {
#pragma unroll
        for (int i = 0; i < 4; ++i)
            async16(aSrc[i] + k0, &lA[(i * 32 + srow) * 64 + scol]);
#pragma unroll
        for (int i = 0; i < 4; ++i)
            async16(bSrc[i] + k0, &lB[(i * 32 + srow) * 64 + scol]);

        asm volatile("s_waitcnt vmcnt(0)" ::: "memory");
        __syncthreads();

#pragma unroll
        for (int kk = 0; kk < 2; ++kk) {
            bf16x8 af[4], bfr[4];
            const int sl = (((kk * 4 + lq) ^ sw8) * 8);
#pragma unroll
            for (int i = 0; i < 4; ++i)
                af[i] = *(const bf16x8*)&lA[(R0 + i * 16 + lr) * 64 + sl];
#pragma unroll
            for (int j = 0; j < 4; ++j)
                bfr[j] = *(const bf16x8*)&lB[(C0 + j * 16 + lr) * 64 + sl];
#pragma unroll
            for (int i = 0; i < 4; ++i)
#pragma unroll
                for (int j = 0; j < 4; ++j)
                    acc[i][j] = __builtin_amdgcn_mfma_f32_16x16x32_bf16(af[i], bfr[j], acc[i][j], 0, 0, 0);
        }
        __syncthreads();
    }

    // epilogue: C/D layout col=lane&15, row=(lane>>4)*4+reg
#pragma unroll
    for (int i = 0; i < 4; ++i) {
#pragma unroll
        for (int j = 0; j < 4; ++j) {
            const int ob = o0 + C0 + j * 16 + lr;
            float bv = 0.f;
            if (ob < Nout)
                bv = isbf ? bf2f(((const u16*)biasv)[ob]) : ((const float*)biasv)[ob];
#pragma unroll
            for (int r = 0; r < 4; ++r) {
                const int row = m0 + R0 + i * 16 + lq * 4 + r;
                const float val = acc[i][j][r] + bv;
                if (EPI == 1) {
                    if (ob < Nout) {
                        const int h = ob / 129;
                        const int rr = ob - h * 129;
                        const size_t mh = (size_t)row * 12 + h;
                        if (rr == 0)       Qf[mh] = val;
                        else if (rr <= 64) Kb[mh * 64 + (rr - 1)]  = f2bf(val);
                        else               Vb[mh * 64 + (rr - 65)] = f2bf(val);
                    }
                } else {
                    if (isbf) Cout16[(size_t)row * ldc + ob] = f2bf(val);
                    else      Cout32[(size_t)row * ldc + ob] = val;
                }
            }
        }
    }
}

// one block per (b,h): softmax over n of q, then cv[d] = sum_n p_n * wcv_n * K[b,n,h,d] / sum
__global__ __launch_bounds__(256) void softmax_cv_kernel(
    const float* __restrict__ Qf, const u16* __restrict__ Kb,
    const void* __restrict__ wcvv, const int* __restrict__ flagp,
    float* __restrict__ cv)
{
    const int isbf = flagp[0];
    const int bh = blockIdx.x;            // 0..767
    const int b = bh / NHh, h = bh - (bh / NHh) * NHh;
    const int t = threadIdx.x;

    __shared__ float sp[1024];
    __shared__ float red[256];

    float q[4];
#pragma unroll
    for (int i = 0; i < 4; ++i) {
        const int n = t + i * 256;
        q[i] = Qf[(size_t)(b * Nn + n) * NHh + h];
    }
    float mx = fmaxf(fmaxf(q[0], q[1]), fmaxf(q[2], q[3]));
    red[t] = mx; __syncthreads();
    for (int off = 128; off; off >>= 1) {
        if (t < off) red[t] = fmaxf(red[t], red[t + off]);
        __syncthreads();
    }
    mx = red[0];
    __syncthreads();

    float sloc = 0.f;
#pragma unroll
    for (int i = 0; i < 4; ++i) {
        const int n = t + i * 256;
        const float e = __expf(q[i] - mx);
        sloc += e;
        const float wv = isbf ? bf2f(((const u16*)wcvv)[n]) : ((const float*)wcvv)[n];
        sp[n] = e * wv;
    }
    red[t] = sloc; __syncthreads();
    for (int off = 128; off; off >>= 1) {
        if (t < off) red[t] += red[t + off];
        __syncthreads();
    }
    const float s = red[0];
    __syncthreads();

    const int d = t & 63, g = t >> 6;     // 4 n-groups of 256
    const u16* Kp = Kb + ((size_t)(b * Nn + g * 256) * NHh + h) * 64 + d;
    const float* pp = sp + g * 256;
    float acc = 0.f;
#pragma unroll 8
    for (int n = 0; n < 256; ++n)
        acc = fmaf(bf2f(Kp[(size_t)n * 768]), pp[n], acc);

    red[t] = acc; __syncthreads();
    if (t < 64) {
        const float tot = red[t] + red[t + 64] + red[t + 128] + red[t + 192];
        cv[(size_t)bh * 64 + t] = tot / s;
    }
}

// in-place V[m, c] = relu(V[m,c]) * cv[(b*12+h)*64+d],  c = h*64+d, b = m>>10
__global__ __launch_bounds__(256) void relu_cv_kernel(
    u16* __restrict__ Vb, const float* __restrict__ cv)
{
    const size_t idx = ((size_t)blockIdx.x * 256 + threadIdx.x) * 8;
    const int c = (int)(idx % 768);
    const size_t m = idx / 768;
    const int b = (int)(m >> 10);
    const int h = c >> 6, d0 = c & 63;
    const float* cvp = cv + ((size_t)b * NHh + h) * 64 + d0;

    u16x8 r = *(const u16x8*)(Vb + idx);
#pragma unroll
    for (int i = 0; i < 8; ++i) {
        const float f = fmaxf(bf2f(r[i]), 0.f) * cvp[i];
        r[i] = f2bf(f);
    }
    *(u16x8*)(Vb + idx) = r;
}

extern "C" void kernel_launch(void* const* d_in, const int* in_sizes, int n_in,
                              void* d_out, int out_size, void* d_ws, size_t ws_size,
                              hipStream_t stream)
{
    const void* x     = d_in[0];
    const void* w_qkv = d_in[1];
    const void* b_qkv = d_in[2];
    const void* w_cv  = d_in[3];
    const void* w_out = d_in[4];
    const void* b_out = d_in[5];

    char* w = (char*)d_ws;
    float* Qf = (float*)w;                                   // 65536*12*4   = 3,145,728 B
    u16*   Kb = (u16*)(w + 3145728);                          // 65536*768*2  = 100,663,296 B
    u16*   Vb = (u16*)(w + 3145728 + 100663296);              // 100,663,296 B
    float* cv = (float*)(w + 3145728 + 2ll * 100663296);      // 768*64*4     = 196,608 B
    int* flag = (int*)(w + 3145728 + 2ll * 100663296 + 196608);
    u16* wqkvb = (u16*)(w + 3145728 + 2ll * 100663296 + 196608 + 4096);  // 1548*768*2 = 2,377,728 B
    u16* woutb = (u16*)((char*)wqkvb + 2377728);                         // 768*768*2  = 1,179,648 B

    // x-bf16 buffer aliases d_out: 100,663,296 B needed, d_out is 201 MB fp32,
    // dead until GEMM2's store (which runs strictly after GEMM1 reads xb).
    u16* xb = (u16*)d_out;

    // dtype detect (bf16 vs fp32 buffers)
    detect_kernel<<<1, 64, 0, stream>>>((const u16*)w_qkv, flag);

    // fp32 -> bf16 pre-convert (no-ops if inputs already bf16)
    cvt_kernel<<<(Mm * Cc) / (256 * 16), 256, 0, stream>>>((const float*)x, xb, (Mm * Cc) / 16, flag);
    cvt_kernel<<<(Oo * Cc + 256 * 16 - 1) / (256 * 16), 256, 0, stream>>>((const float*)w_qkv, wqkvb, (Oo * Cc) / 16, flag);
    cvt_kernel<<<(Cc * Cc) / (256 * 16), 256, 0, stream>>>((const float*)w_out, woutb, (Cc * Cc) / 16, flag);

    // GEMM1: qkv = x @ w_qkv^T + b_qkv, scattered into Qf/Kb/Vb
    gemm_bt<1><<<512 * 13, 256, 0, stream>>>(x, xb, w_qkv, wqkvb, b_qkv, flag,
        Oo, Cc, Cc, Cc, 13, Qf, Kb, Vb, nullptr, nullptr, 0);

    // softmax over n + cv reduction
    softmax_cv_kernel<<<Bb * NHh, 256, 0, stream>>>(Qf, Kb, w_cv, flag, cv);

    // t = relu(v) * cv, in place on Vb
    relu_cv_kernel<<<(Mm * 768) / (256 * 8), 256, 0, stream>>>(Vb, cv);

    // GEMM2: out = t @ w_out^T + b_out  (A = Vb, always internal bf16)
    gemm_bt<2><<<512 * 6, 256, 0, stream>>>(Vb, (const u16*)Vb, w_out, woutb, b_out, flag,
        Cc, Cc, Cc, Cc, 6, nullptr, nullptr, nullptr, (u16*)d_out, (float*)d_out, Cc);
}